// Round 1
// baseline (137.285 us; speedup 1.0000x reference)
//
#include <hip/hip_runtime.h>

// ---- problem constants (from reference) ----
constexpr int T_LEN    = 192000;            // samples per signal
constexpr int N_SIG    = 512;               // 16*32 signals per input
constexpr int FRAME    = 9600;              // 0.4 s @ 24 kHz
constexpr int SHIFT    = 2880;              // 70% overlap
constexpr int SUB      = 960;               // gcd(FRAME, SHIFT)
constexpr int NFRAMES  = (T_LEN - FRAME) / SHIFT + 1;   // 64
constexpr int SUB_PER_SHIFT = SHIFT / SUB;  // 3
constexpr int SUB_PER_FRAME = FRAME / SUB;  // 10
constexpr int NSUB     = (NFRAMES - 1) * SUB_PER_SHIFT + SUB_PER_FRAME; // 199
constexpr int F4_PER_SUB = SUB / 4;         // 240 float4 per sub-block

__device__ __forceinline__ float wave_reduce_f32(float v) {
    #pragma unroll
    for (int off = 32; off > 0; off >>= 1) v += __shfl_xor(v, off);
    return v;
}

__device__ __forceinline__ double wave_reduce_f64(double v) {
    #pragma unroll
    for (int off = 32; off > 0; off >>= 1) v += __shfl_xor(v, off);
    return v;
}

// One block per (input p, signal n). 256 threads = 4 waves.
// Wave w handles sub-blocks w, w+4, ... ; each sub-block = 240 float4,
// coalesced loads, per-lane square-accumulate, wave tree-reduce -> LDS.
// Then wave 0: one frame per lane, gating epilogue in f64.
__global__ __launch_bounds__(256) void dhaspi_loudness_kernel(
    const float* __restrict__ x, const float* __restrict__ y,
    float* __restrict__ lufs_out)
{
    const int bid  = blockIdx.x;
    const int p    = bid >> 9;            // 0 = x, 1 = y
    const int n    = bid & (N_SIG - 1);
    const float* sig = (p == 0 ? x : y) + (size_t)n * T_LEN;
    const float4* sig4 = reinterpret_cast<const float4*>(sig);

    __shared__ float s_sub[NSUB];

    const int tid  = threadIdx.x;
    const int wave = tid >> 6;
    const int lane = tid & 63;

    for (int k = wave; k < NSUB; k += 4) {
        float acc = 0.0f;
        const int base = k * F4_PER_SUB;
        #pragma unroll
        for (int i = 0; i < 4; ++i) {
            int idx = i * 64 + lane;
            if (idx < F4_PER_SUB) {
                float4 v = sig4[base + idx];
                acc += v.x * v.x + v.y * v.y + v.z * v.z + v.w * v.w;
            }
        }
        acc = wave_reduce_f32(acc);
        if (lane == 0) s_sub[k] = acc;
    }
    __syncthreads();

    if (wave == 0) {
        // one frame per lane (NFRAMES == 64 exactly)
        float zs = 0.0f;
        const int b0 = lane * SUB_PER_SHIFT;
        #pragma unroll
        for (int j = 0; j < SUB_PER_FRAME; ++j) zs += s_sub[b0 + j];
        const double z  = (double)zs / (double)FRAME;   // mean-square energy
        const double el = -0.691 + 10.0 * log10(z + 1e-8);

        // absolute gating
        const double ia = (el > -70.0) ? 1.0 : 0.0;
        double sz = wave_reduce_f64(z * ia);
        double si = wave_reduce_f64(ia);
        const double z_ave_a = sz / (si + 1e-8);

        // relative gating: 10 dB below absolute-gated loudness
        const double gamma_r = -0.691 + 10.0 * log10(z_ave_a + 1e-8) - 10.0;
        const double iar = ia * ((el > gamma_r) ? 1.0 : 0.0);
        double sz2 = wave_reduce_f64(z * iar);
        double si2 = wave_reduce_f64(iar);
        const double z_ave_ar = sz2 / (si2 + 1e-8);

        const double lufs = -0.691 + 10.0 * log10(z_ave_ar + 1e-8);
        if (lane == 0) lufs_out[bid] = (float)lufs;
    }
}

// Final hinge-sum over 512 signals: loss = 1e-4 * sum(max(ly - lx, 0)).
__global__ __launch_bounds__(512) void dhaspi_loss_kernel(
    const float* __restrict__ lufs, float* __restrict__ out)
{
    const int tid  = threadIdx.x;
    const int wave = tid >> 6;
    const int lane = tid & 63;

    const float lx = lufs[tid];
    const float ly = lufs[N_SIG + tid];
    const float d  = ly - lx;
    double v = (d > 0.0f) ? (double)d : 0.0;
    v = wave_reduce_f64(v);

    __shared__ double s[8];
    if (lane == 0) s[wave] = v;
    __syncthreads();
    if (tid == 0) {
        double t = 0.0;
        #pragma unroll
        for (int i = 0; i < 8; ++i) t += s[i];
        out[0] = (float)(1e-4 * t);
    }
}

extern "C" void kernel_launch(void* const* d_in, const int* in_sizes, int n_in,
                              void* d_out, int out_size, void* d_ws, size_t ws_size,
                              hipStream_t stream) {
    const float* x = (const float*)d_in[0];
    const float* y = (const float*)d_in[1];
    float* lufs = (float*)d_ws;          // 1024 floats: [x lufs | y lufs]
    float* out  = (float*)d_out;

    dhaspi_loudness_kernel<<<2 * N_SIG, 256, 0, stream>>>(x, y, lufs);
    dhaspi_loss_kernel<<<1, 512, 0, stream>>>(lufs, out);
}

// Round 3
// 120.221 us; speedup vs baseline: 1.1419x; 1.1419x over previous
//
#include <hip/hip_runtime.h>

// ---- problem constants (from reference) ----
constexpr int T_LEN    = 192000;            // samples per signal
constexpr int N_SIG    = 512;               // 16*32 signals per input
constexpr int FRAME    = 9600;              // 0.4 s @ 24 kHz
constexpr int SHIFT    = 2880;              // 70% overlap
constexpr int SUB      = 960;               // gcd(FRAME, SHIFT)
constexpr int NFRAMES  = (T_LEN - FRAME) / SHIFT + 1;   // 64
constexpr int SUB_PER_SHIFT = SHIFT / SUB;  // 3
constexpr int SUB_PER_FRAME = FRAME / SUB;  // 10
constexpr int NSUB     = (NFRAMES - 1) * SUB_PER_SHIFT + SUB_PER_FRAME; // 199
constexpr int F4_PER_SUB = SUB / 4;         // 240 float4 per sub-block

typedef float f32x4 __attribute__((ext_vector_type(4)));

__device__ __forceinline__ float wave_reduce_f32(float v) {
    #pragma unroll
    for (int off = 32; off > 0; off >>= 1) v += __shfl_xor(v, off);
    return v;
}

__device__ __forceinline__ double wave_reduce_f64(double v) {
    #pragma unroll
    for (int off = 32; off > 0; off >>= 1) v += __shfl_xor(v, off);
    return v;
}

// One block per (input p, signal n). 256 threads = 4 waves.
// Wave w handles sub-blocks w, w+4, ...; each sub-block = 240 float4,
// coalesced nontemporal loads, per-lane square-accumulate, wave tree-reduce -> LDS.
// Then wave 0: one frame per lane, gating epilogue in f64.
// (Structure identical to the round-1 PASSING kernel; the ONLY change is the
//  nontemporal hint on the streaming loads — controlled A/B vs round 2's fail.)
__global__ __launch_bounds__(256) void dhaspi_loudness_kernel(
    const float* __restrict__ x, const float* __restrict__ y,
    float* __restrict__ lufs_out)
{
    const int bid  = blockIdx.x;
    const int p    = bid >> 9;            // 0 = x, 1 = y
    const int n    = bid & (N_SIG - 1);
    const float* sig = (p == 0 ? x : y) + (size_t)n * T_LEN;
    const f32x4* sig4 = reinterpret_cast<const f32x4*>(sig);

    __shared__ float s_sub[NSUB];

    const int tid  = threadIdx.x;
    const int wave = tid >> 6;
    const int lane = tid & 63;

    for (int k = wave; k < NSUB; k += 4) {
        float acc = 0.0f;
        const int base = k * F4_PER_SUB;
        #pragma unroll
        for (int i = 0; i < 4; ++i) {
            int idx = i * 64 + lane;
            if (idx < F4_PER_SUB) {
                f32x4 v = __builtin_nontemporal_load(&sig4[base + idx]);
                acc += v.x * v.x + v.y * v.y + v.z * v.z + v.w * v.w;
            }
        }
        acc = wave_reduce_f32(acc);
        if (lane == 0) s_sub[k] = acc;
    }
    __syncthreads();

    if (wave == 0) {
        // one frame per lane (NFRAMES == 64 exactly)
        float zs = 0.0f;
        const int b0 = lane * SUB_PER_SHIFT;
        #pragma unroll
        for (int j = 0; j < SUB_PER_FRAME; ++j) zs += s_sub[b0 + j];
        const double z  = (double)zs / (double)FRAME;   // mean-square energy
        const double el = -0.691 + 10.0 * log10(z + 1e-8);

        // absolute gating
        const double ia = (el > -70.0) ? 1.0 : 0.0;
        double sz = wave_reduce_f64(z * ia);
        double si = wave_reduce_f64(ia);
        const double z_ave_a = sz / (si + 1e-8);

        // relative gating: 10 dB below absolute-gated loudness
        const double gamma_r = -0.691 + 10.0 * log10(z_ave_a + 1e-8) - 10.0;
        const double iar = ia * ((el > gamma_r) ? 1.0 : 0.0);
        double sz2 = wave_reduce_f64(z * iar);
        double si2 = wave_reduce_f64(iar);
        const double z_ave_ar = sz2 / (si2 + 1e-8);

        const double lufs = -0.691 + 10.0 * log10(z_ave_ar + 1e-8);
        if (lane == 0) lufs_out[bid] = (float)lufs;
    }
}

// Final hinge-sum over 512 signals: loss = 1e-4 * sum(max(ly - lx, 0)).
__global__ __launch_bounds__(512) void dhaspi_loss_kernel(
    const float* __restrict__ lufs, float* __restrict__ out)
{
    const int tid  = threadIdx.x;
    const int wave = tid >> 6;
    const int lane = tid & 63;

    const float lx = lufs[tid];
    const float ly = lufs[N_SIG + tid];
    const float d  = ly - lx;
    double v = (d > 0.0f) ? (double)d : 0.0;
    v = wave_reduce_f64(v);

    __shared__ double s[8];
    if (lane == 0) s[wave] = v;
    __syncthreads();
    if (tid == 0) {
        double t = 0.0;
        #pragma unroll
        for (int i = 0; i < 8; ++i) t += s[i];
        out[0] = (float)(1e-4 * t);
    }
}

extern "C" void kernel_launch(void* const* d_in, const int* in_sizes, int n_in,
                              void* d_out, int out_size, void* d_ws, size_t ws_size,
                              hipStream_t stream) {
    const float* x = (const float*)d_in[0];
    const float* y = (const float*)d_in[1];
    float* lufs = (float*)d_ws;          // 1024 floats: [x lufs | y lufs]
    float* out  = (float*)d_out;

    dhaspi_loudness_kernel<<<2 * N_SIG, 256, 0, stream>>>(x, y, lufs);
    dhaspi_loss_kernel<<<1, 512, 0, stream>>>(lufs, out);
}